// Round 3
// baseline (89.868 us; speedup 1.0000x reference)
//
#include <hip/hip_runtime.h>

// ---------------------------------------------------------------------------
// AtomicLinear == x @ W^T + bias.  M=8192, N=2048, K=2048, fp32 in/out.
// R3: same 256x256 tile / BK=32 / ring-4 LDS / counted-vmcnt pipeline as R2,
// but the K-tile body is split into TWO barrier-phases of 16 MFMA each
// (m201-style fine interleave: per phase {ds_reads ∥ stage DMA → bar →
// lgkmcnt(0) → setprio(1) 16xMFMA setprio(0) → bar}), so in-flight MFMAs
// overlap the next phase's LDS reads via wave slip.
// ---------------------------------------------------------------------------

typedef short          bf16x8  __attribute__((ext_vector_type(8)));
typedef unsigned short ushort8 __attribute__((ext_vector_type(8)));
typedef float          f32x4   __attribute__((ext_vector_type(4)));

static constexpr int Mdim = 8192, Ndim = 2048, Kdim = 2048;
static constexpr int BKt  = 32;                     // K per tile
static constexpr int KT2  = Kdim / BKt;             // 64 K-tiles
static constexpr int TILE_BYTES = 256 * BKt * 2;    // 16384 B per 256x32 tile
static constexpr int BUF_BYTES  = 2 * TILE_BYTES;   // 32768 B (A+B per buffer)

__device__ __forceinline__ unsigned short f2bf(float f) {
    unsigned u = __float_as_uint(f);
    u += 0x7fffu + ((u >> 16) & 1u);
    return (unsigned short)(u >> 16);
}

// ---------------------------------------------------------------------------
// Prepass (unchanged from R2, measured 0 bank conflicts downstream):
// fp32 [R][2048] row-major -> bf16 tiles of 256 rows x 32 cols.  Within a
// tile: 128 lines x 128 B; line L holds rows {2L, 2L+1}; 16B chunk for
// (row r, cols c0..c0+7) sits at slot = (c0/8 | ((r&1)<<2)) ^ ((r>>1)&7).
// ---------------------------------------------------------------------------
__global__ void conv2(const float* __restrict__ src, unsigned short* __restrict__ dst) {
    int g    = blockIdx.x * 256 + threadIdx.x;    // one thread per 16B chunk
    int idx  = g & 1023;                          // chunk within tile
    int tile = g >> 10;
    int line = idx >> 3, slot = idx & 7;
    int cs   = slot ^ (line & 7);                 // = chunk | (sub<<2)
    int r    = 2 * line + (cs >> 2);
    int c0   = (cs & 3) << 3;
    int kt   = tile & 63, rt = tile >> 6;

    const float* p = src + (size_t)(rt * 256 + r) * 2048 + kt * 32 + c0;
    float4 v0 = *(const float4*)p;
    float4 v1 = *(const float4*)(p + 4);
    ushort8 o;
    o[0] = f2bf(v0.x); o[1] = f2bf(v0.y); o[2] = f2bf(v0.z); o[3] = f2bf(v0.w);
    o[4] = f2bf(v1.x); o[5] = f2bf(v1.y); o[6] = f2bf(v1.z); o[7] = f2bf(v1.w);
    *(ushort8*)(dst + (size_t)g * 8) = o;         // linear/coalesced write
}

#define GL_LDS16(gsrc, ldst)                                                    \
    __builtin_amdgcn_global_load_lds(                                           \
        (const __attribute__((address_space(1))) void*)(gsrc),                  \
        (__attribute__((address_space(3))) void*)(ldst), 16, 0, 0)

// One K-tile = two fine phases.  VM = vmcnt to wait at end of tile (-1: none),
// STG = whether to stage tile t+3 (A-half in phase 1, B-half in phase 2).
template <int VM, bool STG>
__device__ __forceinline__ void tile_body(unsigned aA, unsigned bA, f32x4 acc[8][4],
                                          const char* gA, const char* gB, char* lb) {
    bf16x8 af0[4], af1[4], bv[4];
    // ---------------- phase 1: mi 0-3 ----------------
#pragma unroll
    for (int i = 0; i < 4; ++i)
        asm volatile("ds_read_b128 %0, %1 offset:%2"
                     : "=v"(af0[i]) : "v"(aA), "i"(i * 1024));
#pragma unroll
    for (int i = 0; i < 4; ++i)
        asm volatile("ds_read_b128 %0, %1 offset:%2"
                     : "=v"(bv[i]) : "v"(bA), "i"(i * 1024));
    if constexpr (STG) { GL_LDS16(gA, lb); GL_LDS16(gA + 8192, lb + 8192); }
    __builtin_amdgcn_s_barrier();
    asm volatile("s_waitcnt lgkmcnt(0)" ::: "memory");
    __builtin_amdgcn_sched_barrier(0);            // rule #18
    __builtin_amdgcn_s_setprio(1);
#pragma unroll
    for (int mi = 0; mi < 4; ++mi)
#pragma unroll
        for (int ni = 0; ni < 4; ++ni)
            acc[mi][ni] = __builtin_amdgcn_mfma_f32_16x16x32_bf16(
                af0[mi], bv[ni], acc[mi][ni], 0, 0, 0);
    __builtin_amdgcn_s_setprio(0);
    __builtin_amdgcn_s_barrier();
    // ---------------- phase 2: mi 4-7 ----------------
#pragma unroll
    for (int i = 0; i < 4; ++i)
        asm volatile("ds_read_b128 %0, %1 offset:%2"
                     : "=v"(af1[i]) : "v"(aA), "i"(4096 + i * 1024));
    if constexpr (STG) { GL_LDS16(gB, lb + 16384); GL_LDS16(gB + 8192, lb + 24576); }
    if constexpr (VM == 8)      asm volatile("s_waitcnt vmcnt(8)" ::: "memory");
    else if constexpr (VM == 4) asm volatile("s_waitcnt vmcnt(4)" ::: "memory");
    else if constexpr (VM == 0) asm volatile("s_waitcnt vmcnt(0)" ::: "memory");
    __builtin_amdgcn_s_barrier();
    asm volatile("s_waitcnt lgkmcnt(0)" ::: "memory");
    __builtin_amdgcn_sched_barrier(0);
    __builtin_amdgcn_s_setprio(1);
#pragma unroll
    for (int mi = 0; mi < 4; ++mi)
#pragma unroll
        for (int ni = 0; ni < 4; ++ni)
            acc[mi + 4][ni] = __builtin_amdgcn_mfma_f32_16x16x32_bf16(
                af1[mi], bv[ni], acc[mi + 4][ni], 0, 0, 0);
    __builtin_amdgcn_s_setprio(0);
    __builtin_amdgcn_s_barrier();
}

// 256x256 block tile, 512 threads (8 waves as 2M x 4N), wave tile 128x64.
__global__ __launch_bounds__(512, 2) void gemm3(
    const unsigned short* __restrict__ xa, const unsigned short* __restrict__ wb,
    const float* __restrict__ bias, float* __restrict__ out) {
    extern __shared__ char smem[];                // 4 x 32 KB ring

    const int tid  = threadIdx.x;
    const int lane = tid & 63, wid = tid >> 6;
    const int wr   = wid >> 2;                    // 0..1
    const int wc   = wid & 3;                     // 0..3
    const int fr   = lane & 15, fq = lane >> 4;
    const int l3   = fr >> 1;
    const int slot = (fq | ((fr & 1) << 2)) ^ l3; // swizzle slot (const per lane)

    const int bid = blockIdx.x;                   // 256 blocks = 1/CU
    const int nt  = bid & 7;                      // XCD-local B panel (T1)
    const int mt  = bid >> 3;                     // 0..31

    const char* aT = (const char*)xa + (size_t)mt * KT2 * TILE_BYTES;
    const char* bT = (const char*)wb + (size_t)nt * KT2 * TILE_BYTES;

    const unsigned ldsBase = (unsigned)(size_t)smem;
    const unsigned aAddr0  = ldsBase +
        (unsigned)(((wr * 64 + l3) * 64 + slot * 8) * 2);
    const unsigned bAddr0  = ldsBase + 16384u +
        (unsigned)(((wc * 32 + l3) * 64 + slot * 8) * 2);

    f32x4 acc[8][4];
#pragma unroll
    for (int i = 0; i < 8; ++i)
#pragma unroll
        for (int j = 0; j < 4; ++j)
            acc[i][j] = f32x4{0.f, 0.f, 0.f, 0.f};

#define STAGE(t_)                                                               \
    {                                                                           \
        const char* gA = aT + (size_t)(t_)*TILE_BYTES + tid * 16;               \
        const char* gB = bT + (size_t)(t_)*TILE_BYTES + tid * 16;               \
        char* lb = smem + ((t_) & 3) * BUF_BYTES + tid * 16;                    \
        GL_LDS16(gA, lb);                                                       \
        GL_LDS16(gA + 8192, lb + 8192);                                         \
        GL_LDS16(gB, lb + 16384);                                               \
        GL_LDS16(gB + 8192, lb + 24576);                                        \
    }

    // Prologue: depth-3 prefetch; wait->8 = tile 0 resident.
    STAGE(0);
    STAGE(1);
    STAGE(2);
    asm volatile("s_waitcnt vmcnt(8)" ::: "memory");
    __builtin_amdgcn_s_barrier();

    // Steady state: t = 0..60; stage tile t+3 split across the two phases.
    for (int t = 0; t < KT2 - 3; ++t) {
        const unsigned ba = (unsigned)((t & 3) * BUF_BYTES);
        const int tn = t + 3;
        tile_body<8, true>(aAddr0 + ba, bAddr0 + ba, acc,
                           aT + (size_t)tn * TILE_BYTES + tid * 16,
                           bT + (size_t)tn * TILE_BYTES + tid * 16,
                           smem + (tn & 3) * BUF_BYTES + tid * 16);
    }
    // Drain: tiles 61, 62, 63.
    tile_body<4, false>(aAddr0 + 1u * BUF_BYTES, bAddr0 + 1u * BUF_BYTES, acc,
                        nullptr, nullptr, nullptr);
    tile_body<0, false>(aAddr0 + 2u * BUF_BYTES, bAddr0 + 2u * BUF_BYTES, acc,
                        nullptr, nullptr, nullptr);
    tile_body<-1, false>(aAddr0 + 3u * BUF_BYTES, bAddr0 + 3u * BUF_BYTES, acc,
                         nullptr, nullptr, nullptr);

    // Epilogue: C/D layout col = lane&15, row = (lane>>4)*4 + reg.
    const int gcol  = nt * 256 + wc * 64;
    const int grow0 = mt * 256 + wr * 128 + fq * 4;
#pragma unroll
    for (int ni = 0; ni < 4; ++ni) {
        const int cn = gcol + ni * 16 + fr;
        const float bv2 = bias[cn];
#pragma unroll
        for (int mi = 0; mi < 8; ++mi) {
            const int rm = grow0 + mi * 16;
#pragma unroll
            for (int rr = 0; rr < 4; ++rr)
                out[(size_t)(rm + rr) * Ndim + cn] = acc[mi][ni][rr] + bv2;
        }
    }
#undef STAGE
}

// Correct-but-slow fp32 fallback if workspace is too small for bf16 copies.
__global__ void fallback_gemm(const float* __restrict__ x, const float* __restrict__ w,
                              const float* __restrict__ bias, float* __restrict__ out) {
    __shared__ float As[64][17];
    __shared__ float Bs[64][17];
    int tx = threadIdx.x & 15, ty = threadIdx.x >> 4;
    int m0 = blockIdx.y * 64, n0 = blockIdx.x * 64;
    float acc[4][4] = {};
    for (int k0 = 0; k0 < Kdim; k0 += 16) {
#pragma unroll
        for (int i = 0; i < 4; ++i) {
            int idx = threadIdx.x + i * 256;
            int rr = idx >> 4, cc = idx & 15;
            As[rr][cc] = x[(size_t)(m0 + rr) * Kdim + k0 + cc];
            Bs[rr][cc] = w[(size_t)(n0 + rr) * Kdim + k0 + cc];
        }
        __syncthreads();
#pragma unroll
        for (int kk = 0; kk < 16; ++kk) {
            float a[4], b[4];
#pragma unroll
            for (int i = 0; i < 4; ++i) a[i] = As[ty * 4 + i][kk];
#pragma unroll
            for (int j = 0; j < 4; ++j) b[j] = Bs[tx * 4 + j][kk];
#pragma unroll
            for (int i = 0; i < 4; ++i)
#pragma unroll
                for (int j = 0; j < 4; ++j) acc[i][j] += a[i] * b[j];
        }
        __syncthreads();
    }
#pragma unroll
    for (int i = 0; i < 4; ++i)
#pragma unroll
        for (int j = 0; j < 4; ++j) {
            int gm = m0 + ty * 4 + i, gn = n0 + tx * 4 + j;
            out[(size_t)gm * Ndim + gn] = acc[i][j] + bias[gn];
        }
}

extern "C" void kernel_launch(void* const* d_in, const int* in_sizes, int n_in,
                              void* d_out, int out_size, void* d_ws, size_t ws_size,
                              hipStream_t stream) {
    const float* x    = (const float*)d_in[0];
    const float* w    = (const float*)d_in[1];
    const float* bias = (const float*)d_in[2];
    float* out        = (float*)d_out;

    const size_t needA = (size_t)Mdim * Kdim * sizeof(unsigned short);
    const size_t needB = (size_t)Ndim * Kdim * sizeof(unsigned short);

    if (ws_size >= needA + needB) {
        unsigned short* xa = (unsigned short*)d_ws;
        unsigned short* wb = xa + (size_t)Mdim * Kdim;
        conv2<<<(Mdim / 256) * KT2 * 1024 / 256, 256, 0, stream>>>(x, xa);
        conv2<<<(Ndim / 256) * KT2 * 1024 / 256, 256, 0, stream>>>(w, wb);

        (void)hipFuncSetAttribute((const void*)gemm3,
                                  hipFuncAttributeMaxDynamicSharedMemorySize,
                                  4 * BUF_BYTES);
        gemm3<<<(Mdim / 256) * (Ndim / 256), 512, 4 * BUF_BYTES, stream>>>(
            xa, wb, bias, out);
    } else {
        dim3 grid(Ndim / 64, Mdim / 64);
        fallback_gemm<<<grid, 256, 0, stream>>>(x, w, bias, out);
    }
}

// Round 4
// 88.407 us; speedup vs baseline: 1.0165x; 1.0165x over previous
//
#include <hip/hip_runtime.h>

// ---------------------------------------------------------------------------
// AtomicLinear == x @ W^T + bias.  M=8192, N=2048, K=2048, fp32 in/out.
// R4: m201-style 8-phase iteration. 256x256 tile, BK=64, 2 K-tiles/iter,
// 2 LDS double-buffers (128 KiB), half-tile staging (1 half = 16 KB = 2
// global_load_lds/thread) one per phase, vmcnt(4) only at phases 4 & 8.
// Frag lgkm-waits are SSA-tied ("+v") to the MFMA inputs -> no sched_barrier
// pinning. Prepass bakes the half-grouped swizzled LDS image into d_ws.
// ---------------------------------------------------------------------------

typedef short          bf16x8  __attribute__((ext_vector_type(8)));
typedef unsigned short ushort8 __attribute__((ext_vector_type(8)));
typedef float          f32x4   __attribute__((ext_vector_type(4)));

static constexpr int Mdim = 8192, Ndim = 2048, Kdim = 2048;
static constexpr int BK4 = 64;
static constexpr int KT4 = Kdim / BK4;        // 32 K-tiles
static constexpr int TB4 = 256 * BK4 * 2;     // 32768 B per 256x64 tile
// tile image: [half0 16KB][half1 16KB]; half = 128 prows x 128 B;
// prow byte layout: 8 slots of 16B, slot = c ^ (p&7), c = K-chunk 0..7.

__device__ __forceinline__ unsigned short f2bf(float f) {
    unsigned u = __float_as_uint(f);
    u += 0x7fffu + ((u >> 16) & 1u);
    return (unsigned short)(u >> 16);
}

__device__ __forceinline__ bf16x8 mfma_(bf16x8 a, bf16x8 b);  // unused decl guard

// Prepass: fp32 row-major -> half-grouped swizzled bf16 tile image.
// ISA=true: A (x, halves split at row%128 < 64); false: B (w, row%64 < 32).
template <bool ISA>
__global__ void conv4(const float* __restrict__ src, unsigned short* __restrict__ dst) {
    int g    = blockIdx.x * 256 + threadIdx.x;   // one thread per 16B chunk
    int tile = g >> 11;                          // 2048 chunks per tile
    int idx  = g & 2047;
    int h    = idx >> 10;
    int rem  = idx & 1023;
    int p    = rem >> 3, s = rem & 7;
    int c    = s ^ (p & 7);
    int kt   = tile & 31, rt = tile >> 5;
    int r;
    if constexpr (ISA) r = (p >> 6) * 128 + h * 64 + (p & 63);
    else               r = (p >> 5) * 64  + h * 32 + (p & 31);

    const float* q = src + (size_t)(rt * 256 + r) * 2048 + kt * 64 + c * 8;
    float4 v0 = *(const float4*)q;
    float4 v1 = *(const float4*)(q + 4);
    ushort8 o;
    o[0] = f2bf(v0.x); o[1] = f2bf(v0.y); o[2] = f2bf(v0.z); o[3] = f2bf(v0.w);
    o[4] = f2bf(v1.x); o[5] = f2bf(v1.y); o[6] = f2bf(v1.z); o[7] = f2bf(v1.w);
    *(ushort8*)(dst + (size_t)g * 8) = o;
}

#define GL_LDS16(gsrc, ldst)                                                    \
    __builtin_amdgcn_global_load_lds(                                           \
        (const __attribute__((address_space(1))) void*)(gsrc),                  \
        (__attribute__((address_space(3))) void*)(ldst), 16, 0, 0)

// Stage one 16 KB half-tile: 2 loads/thread, fully linear.
__device__ __forceinline__ void stage_half(const char* src, char* smem,
                                           unsigned ldsoff, int tid) {
    GL_LDS16(src + tid * 16,        smem + ldsoff + tid * 16);
    GL_LDS16(src + 8192 + tid * 16, smem + ldsoff + 8192 + tid * 16);
}

template <int OFF>
__device__ __forceinline__ void readA8(bf16x8 af[4][2], unsigned k0, unsigned k1) {
#pragma unroll
    for (int mi = 0; mi < 4; ++mi) {
        asm volatile("ds_read_b128 %0, %1 offset:%2"
                     : "=v"(af[mi][0]) : "v"(k0), "i"(OFF + mi * 2048));
        asm volatile("ds_read_b128 %0, %1 offset:%2"
                     : "=v"(af[mi][1]) : "v"(k1), "i"(OFF + mi * 2048));
    }
}
template <int OFF>
__device__ __forceinline__ void readB4(bf16x8 bf[2][2], unsigned k0, unsigned k1) {
#pragma unroll
    for (int ni = 0; ni < 2; ++ni) {
        asm volatile("ds_read_b128 %0, %1 offset:%2"
                     : "=v"(bf[ni][0]) : "v"(k0), "i"(OFF + ni * 2048));
        asm volatile("ds_read_b128 %0, %1 offset:%2"
                     : "=v"(bf[ni][1]) : "v"(k1), "i"(OFF + ni * 2048));
    }
}

// lgkm waits SSA-tied to the registers the MFMAs will consume.
#define TIE12(af, bf)                                                           \
    asm volatile("s_waitcnt lgkmcnt(0)"                                         \
                 : "+v"(af[0][0]), "+v"(af[0][1]), "+v"(af[1][0]),              \
                   "+v"(af[1][1]), "+v"(af[2][0]), "+v"(af[2][1]),              \
                   "+v"(af[3][0]), "+v"(af[3][1]), "+v"(bf[0][0]),              \
                   "+v"(bf[0][1]), "+v"(bf[1][0]), "+v"(bf[1][1]))
#define TIE8(af)                                                                \
    asm volatile("s_waitcnt lgkmcnt(0)"                                         \
                 : "+v"(af[0][0]), "+v"(af[0][1]), "+v"(af[1][0]),              \
                   "+v"(af[1][1]), "+v"(af[2][0]), "+v"(af[2][1]),              \
                   "+v"(af[3][0]), "+v"(af[3][1]))
#define TIE4(bf)                                                                \
    asm volatile("s_waitcnt lgkmcnt(0)"                                         \
                 : "+v"(bf[0][0]), "+v"(bf[0][1]), "+v"(bf[1][0]), "+v"(bf[1][1]))

template <int RB, int CB>
__device__ __forceinline__ void mfmaQ(f32x4 acc[8][4], bf16x8 af[4][2],
                                      bf16x8 bf[2][2]) {
    __builtin_amdgcn_s_setprio(1);
#pragma unroll
    for (int kk = 0; kk < 2; ++kk)
#pragma unroll
        for (int mi = 0; mi < 4; ++mi)
#pragma unroll
            for (int ni = 0; ni < 2; ++ni)
                acc[RB + mi][CB + ni] = __builtin_amdgcn_mfma_f32_16x16x32_bf16(
                    af[mi][kk], bf[ni][kk], acc[RB + mi][CB + ni], 0, 0, 0);
    __builtin_amdgcn_s_setprio(0);
}

#define BAR() __builtin_amdgcn_s_barrier()

// One K-tile (4 phases).  SMASK bit p-1 = phase p stages; VM = vmcnt at ph4.
template <int SMASK, int VM>
__device__ __forceinline__ void half_iter(
    unsigned aK0, unsigned aK1, unsigned bK0, unsigned bK1,
    f32x4 acc[8][4], bf16x8 af[4][2], bf16x8 bfA[2][2], bf16x8 bfB[2][2],
    const char* s1, unsigned d1, const char* s2, unsigned d2,
    const char* s3, unsigned d3, const char* s4, unsigned d4,
    char* smem, int tid) {
    // phase 1: Q(A0,B0)
    readA8<0>(af, aK0, aK1);
    readB4<0>(bfA, bK0, bK1);
    if constexpr (SMASK & 1) stage_half(s1, smem, d1, tid);
    BAR();
    TIE12(af, bfA);
    mfmaQ<0, 0>(acc, af, bfA);
    BAR();
    // phase 2: Q(A1,B0)
    readA8<16384>(af, aK0, aK1);
    if constexpr (SMASK & 2) stage_half(s2, smem, d2, tid);
    BAR();
    TIE8(af);
    mfmaQ<4, 0>(acc, af, bfA);
    BAR();
    // phase 3: Q(A1,B1)
    readB4<16384>(bfB, bK0, bK1);
    if constexpr (SMASK & 4) stage_half(s3, smem, d3, tid);
    BAR();
    TIE4(bfB);
    mfmaQ<4, 2>(acc, af, bfB);
    BAR();
    // phase 4: Q(A0,B1)
    readA8<0>(af, aK0, aK1);
    if constexpr (SMASK & 8) stage_half(s4, smem, d4, tid);
    BAR();
    TIE8(af);
    mfmaQ<0, 2>(acc, af, bfB);
    if constexpr (VM == 4) asm volatile("s_waitcnt vmcnt(4)" ::: "memory");
    else if constexpr (VM == 0) asm volatile("s_waitcnt vmcnt(0)" ::: "memory");
    BAR();
}

// 256x256 block tile, 512 threads (8 waves 2M x 4N), wave tile 128x64.
__global__ __launch_bounds__(512, 2) void gemm4(
    const unsigned short* __restrict__ xa, const unsigned short* __restrict__ wb,
    const float* __restrict__ bias, float* __restrict__ out) {
    extern __shared__ char smem[];               // 2 bufs x 64 KB

    const int tid  = threadIdx.x;
    const int lane = tid & 63, wid = tid >> 6;
    const int wr   = wid >> 2;                   // 0..1
    const int wc   = wid & 3;                    // 0..3
    const int fr   = lane & 15, fq = lane >> 4;

    const int bid = blockIdx.x;                  // 256 blocks = 1/CU
    const int nt  = bid & 7;                     // XCD-local B panel (T1)
    const int mt  = bid >> 3;                    // 0..31

    const char* aT = (const char*)xa + (size_t)mt * KT4 * TB4;
    const char* bT = (const char*)wb + (size_t)nt * KT4 * TB4;

    const unsigned lds0  = (unsigned)(size_t)smem;
    const int slot0 = fq ^ (fr & 7);
    const int slot1 = (4 + fq) ^ (fr & 7);
    const unsigned aRow = (unsigned)((wr * 64 + fr) * 128);
    const unsigned bRow = (unsigned)((wc * 32 + fr) * 128);
    const unsigned aK0_0 = lds0 + aRow + slot0 * 16;
    const unsigned aK1_0 = lds0 + aRow + slot1 * 16;
    const unsigned bK0_0 = lds0 + 32768u + bRow + slot0 * 16;
    const unsigned bK1_0 = lds0 + 32768u + bRow + slot1 * 16;
    const unsigned aK0_1 = aK0_0 + 65536u, aK1_1 = aK1_0 + 65536u;
    const unsigned bK0_1 = bK0_0 + 65536u, bK1_1 = bK1_0 + 65536u;

    f32x4 acc[8][4];
#pragma unroll
    for (int i = 0; i < 8; ++i)
#pragma unroll
        for (int j = 0; j < 4; ++j)
            acc[i][j] = f32x4{0.f, 0.f, 0.f, 0.f};
    bf16x8 af[4][2], bfA[2][2], bfB[2][2];

    // Prologue: tile0 all 4 halves -> buf0; tile1 B0,A1 -> buf1.
    stage_half(aT,                smem, 0,     tid);     // A0(0)
    stage_half(aT + 16384,        smem, 16384, tid);     // A1(0)
    stage_half(bT,                smem, 32768, tid);     // B0(0)
    stage_half(bT + 16384,        smem, 49152, tid);     // B1(0)
    stage_half(bT + TB4,          smem, 98304, tid);     // B0(1)
    stage_half(aT + TB4 + 16384,  smem, 81920, tid);     // A1(1)
    asm volatile("s_waitcnt vmcnt(4)" ::: "memory");     // tile0 resident
    BAR();

    // Steady: 15 iters, each = tiles {2i (buf0), 2i+1 (buf1)}, stages per plan:
    // ph1 B1(t+1)  ph2 A0(t+1)  ph3 B0(t+2)  ph4 A1(t+2)
    // ph5 B1(t+2)  ph6 A0(t+2)  ph7 B0(t+3)  ph8 A1(t+3)
#pragma unroll 1
    for (int it = 0; it < 15; ++it) {
        const char* a1 = aT + (size_t)(2 * it + 1) * TB4;
        const char* a2 = a1 + TB4;
        const char* a3 = a2 + TB4;
        const char* b1 = bT + (size_t)(2 * it + 1) * TB4;
        const char* b2 = b1 + TB4;
        const char* b3 = b2 + TB4;
        half_iter<0xF, 4>(aK0_0, aK1_0, bK0_0, bK1_0, acc, af, bfA, bfB,
                          b1 + 16384, 114688u, a1, 65536u,
                          b2, 32768u, a2 + 16384, 16384u, smem, tid);
        half_iter<0xF, 4>(aK0_1, aK1_1, bK0_1, bK1_1, acc, af, bfA, bfB,
                          b2 + 16384, 49152u, a2, 0u,
                          b3, 98304u, a3 + 16384, 81920u, smem, tid);
    }
    // Tail: tiles 30 (buf0, stage tile31's B1/A0, drain vmcnt), 31 (buf1).
    {
        const char* a31 = aT + (size_t)31 * TB4;
        const char* b31 = bT + (size_t)31 * TB4;
        half_iter<0x3, 0>(aK0_0, aK1_0, bK0_0, bK1_0, acc, af, bfA, bfB,
                          b31 + 16384, 114688u, a31, 65536u,
                          aT, 0u, aT, 0u, smem, tid);
        half_iter<0x0, -1>(aK0_1, aK1_1, bK0_1, bK1_1, acc, af, bfA, bfB,
                           aT, 0u, aT, 0u, aT, 0u, aT, 0u, smem, tid);
    }

    // Epilogue. acc[ar][ac]: row = wr*128 + (ar>>2)*64 + (ar&3)*16 + fq*4 + rr;
    //                        col = wc*64 + (ac>>1)*32 + (ac&1)*16 + fr.
    const int gr0 = mt * 256 + wr * 128 + fq * 4;
    const int gc0 = nt * 256 + wc * 64;
#pragma unroll
    for (int ac = 0; ac < 4; ++ac) {
        const int cn = gc0 + (ac >> 1) * 32 + (ac & 1) * 16 + fr;
        const float bv = bias[cn];
#pragma unroll
        for (int ar = 0; ar < 8; ++ar) {
            const int rm = gr0 + (ar >> 2) * 64 + (ar & 3) * 16;
#pragma unroll
            for (int rr = 0; rr < 4; ++rr)
                out[(size_t)(rm + rr) * Ndim + cn] = acc[ar][ac][rr] + bv;
        }
    }
}

// Correct-but-slow fp32 fallback if workspace is too small for bf16 copies.
__global__ void fallback_gemm(const float* __restrict__ x, const float* __restrict__ w,
                              const float* __restrict__ bias, float* __restrict__ out) {
    __shared__ float As[64][17];
    __shared__ float Bs[64][17];
    int tx = threadIdx.x & 15, ty = threadIdx.x >> 4;
    int m0 = blockIdx.y * 64, n0 = blockIdx.x * 64;
    float acc[4][4] = {};
    for (int k0 = 0; k0 < Kdim; k0 += 16) {
#pragma unroll
        for (int i = 0; i < 4; ++i) {
            int idx = threadIdx.x + i * 256;
            int rr = idx >> 4, cc = idx & 15;
            As[rr][cc] = x[(size_t)(m0 + rr) * Kdim + k0 + cc];
            Bs[rr][cc] = w[(size_t)(n0 + rr) * Kdim + k0 + cc];
        }
        __syncthreads();
#pragma unroll
        for (int kk = 0; kk < 16; ++kk) {
            float a[4], b[4];
#pragma unroll
            for (int i = 0; i < 4; ++i) a[i] = As[ty * 4 + i][kk];
#pragma unroll
            for (int j = 0; j < 4; ++j) b[j] = Bs[tx * 4 + j][kk];
#pragma unroll
            for (int i = 0; i < 4; ++i)
#pragma unroll
                for (int j = 0; j < 4; ++j) acc[i][j] += a[i] * b[j];
        }
        __syncthreads();
    }
#pragma unroll
    for (int i = 0; i < 4; ++i)
#pragma unroll
        for (int j = 0; j < 4; ++j) {
            int gm = m0 + ty * 4 + i, gn = n0 + tx * 4 + j;
            out[(size_t)gm * Ndim + gn] = acc[i][j] + bias[gn];
        }
}

extern "C" void kernel_launch(void* const* d_in, const int* in_sizes, int n_in,
                              void* d_out, int out_size, void* d_ws, size_t ws_size,
                              hipStream_t stream) {
    const float* x    = (const float*)d_in[0];
    const float* w    = (const float*)d_in[1];
    const float* bias = (const float*)d_in[2];
    float* out        = (float*)d_out;

    const size_t needA = (size_t)Mdim * Kdim * sizeof(unsigned short);
    const size_t needB = (size_t)Ndim * Kdim * sizeof(unsigned short);

    if (ws_size >= needA + needB) {
        unsigned short* xa = (unsigned short*)d_ws;
        unsigned short* wb = xa + (size_t)Mdim * Kdim;
        conv4<true><<<(Mdim * Kdim / 8) / 256, 256, 0, stream>>>(x, xa);
        conv4<false><<<(Ndim * Kdim / 8) / 256, 256, 0, stream>>>(w, wb);

        (void)hipFuncSetAttribute((const void*)gemm4,
                                  hipFuncAttributeMaxDynamicSharedMemorySize,
                                  131072);
        gemm4<<<(Mdim / 256) * (Ndim / 256), 512, 131072, stream>>>(
            xa, wb, bias, out);
    } else {
        dim3 grid(Ndim / 64, Mdim / 64);
        fallback_gemm<<<grid, 256, 0, stream>>>(x, w, bias, out);
    }
}